// Round 7
// baseline (608.270 us; speedup 1.0000x reference)
//
#include <hip/hip_runtime.h>
#include <hip/hip_bf16.h>

#define NQ   50000
#define NKV  50000
#define CC   128
#define GG   8
#define SS   16
#define CSH  16

typedef short    bf16x8 __attribute__((ext_vector_type(8)));
typedef float    f32x4  __attribute__((ext_vector_type(4)));
typedef unsigned u32x4  __attribute__((ext_vector_type(4)));
typedef unsigned u32x2  __attribute__((ext_vector_type(2)));
typedef int      i32x4  __attribute__((ext_vector_type(4)));

__device__ __forceinline__ float bf_lo(unsigned u){ union{unsigned x; float f;} v; v.x = u << 16;        return v.f; }
__device__ __forceinline__ float bf_hi(unsigned u){ union{unsigned x; float f;} v; v.x = u & 0xffff0000u; return v.f; }
__device__ __forceinline__ unsigned short f2bfu(float f){
    __hip_bfloat16 h = __float2bfloat16(f);
    return *reinterpret_cast<unsigned short*>(&h);
}
__device__ __forceinline__ short f2bfs(float f){
    __hip_bfloat16 h = __float2bfloat16(f);
    return *reinterpret_cast<short*>(&h);
}

// Load 16 contiguous bf16 (32B, >=16B aligned) -> 16 fp32
__device__ __forceinline__ void load16bf(const __hip_bfloat16* ptr, float* o){
    const u32x4* p4 = reinterpret_cast<const u32x4*>(ptr);
    u32x4 a = p4[0]; u32x4 b = p4[1];
    o[0]=bf_lo(a[0]);  o[1]=bf_hi(a[0]);  o[2]=bf_lo(a[1]);  o[3]=bf_hi(a[1]);
    o[4]=bf_lo(a[2]);  o[5]=bf_hi(a[2]);  o[6]=bf_lo(a[3]);  o[7]=bf_hi(a[3]);
    o[8]=bf_lo(b[0]);  o[9]=bf_hi(b[0]);  o[10]=bf_lo(b[1]); o[11]=bf_hi(b[1]);
    o[12]=bf_lo(b[2]); o[13]=bf_hi(b[2]); o[14]=bf_lo(b[3]); o[15]=bf_hi(b[3]);
}

// Load 8 contiguous f32 (32B), convert to bf16x8 fragment
__device__ __forceinline__ bf16x8 cvt8(const float* p){
    const f32x4* q = reinterpret_cast<const f32x4*>(p);
    f32x4 u = q[0], v = q[1];
    bf16x8 r;
    r[0]=f2bfs(u[0]); r[1]=f2bfs(u[1]); r[2]=f2bfs(u[2]); r[3]=f2bfs(u[3]);
    r[4]=f2bfs(v[0]); r[5]=f2bfs(v[1]); r[6]=f2bfs(v[2]); r[7]=f2bfs(v[3]);
    return r;
}

// ---------------------------------------------------------------------------
// Kernel 1: Q/K/V projections, K+V fused over one read of x2.
// Block = 256 threads = 4 waves, 128 rows/block (32 rows/wave). 32 KB LDS.
// y=0: Q from x. y=1: stage Wk -> K tiles -> restage Wv (same LDS, barriers)
// -> V tiles; x2 fragments live in registers across both phases, so x2 is
// read ONCE (round-6 read it twice, 25.6 MB extra).
// All stores plain (round-6 lesson: NT stores cost write amplification,
// WRITE_SIZE 25->38 MB, and slowed both kernels).
// K/V land interleaved in KVf rows of 256 elems: [K 0..127 | V 128..255].
// ---------------------------------------------------------------------------
__global__ __launch_bounds__(256) void qkv_gemm(
    const float* __restrict__ x,
    const float* __restrict__ x2,
    const float* __restrict__ Wq, const float* __restrict__ Wk,
    const float* __restrict__ Wv,
    const float* __restrict__ bq, const float* __restrict__ bk,
    const float* __restrict__ bv,
    __hip_bfloat16* __restrict__ Qf,     // (NQ, 128)
    __hip_bfloat16* __restrict__ KVf)    // (NKV, 256) interleaved K|V
{
    __shared__ short lds16[16384];   // 32 KB: 8 tiles x 4 kb x 64 lanes x 8 halfwords

    const int tid  = threadIdx.x;
    const int wave = tid >> 6;
    const int lane = tid & 63;
    const int r    = lane & 15;
    const int kq   = lane >> 4;
    const int base = blockIdx.x * 128 + wave * 32;

    // stage one 128x128 f32 W into LDS (bf16, MFMA A-fragment order),
    // lane-contiguous global reads (32B stride -> full cache lines)
    auto stageW = [&](const float* __restrict__ W){
        #pragma unroll
        for (int i = 0; i < 8; ++i) {
            const int o   = i * 2048 + tid * 8;    // linear f32 offset in W
            const bf16x8 v = cvt8(W + o);
            const int row = o >> 7, col = o & 127;
            const int lchunk = (((row >> 4) * 4 + (col >> 5)) << 6)
                             + (((col >> 3) & 3) << 4) + (row & 15);
            *reinterpret_cast<bf16x8*>(&lds16[lchunk * 8]) = v;
        }
    };

    // load this wave's 32 source rows as B-fragments (2 m-tiles x 4 k-blocks)
    auto loadB = [&](const float* __restrict__ src, bf16x8 (&bfrag)[2][4]){
        #pragma unroll
        for (int mt = 0; mt < 2; ++mt) {
            int row = base + mt * 16 + r;
            if (row >= NQ) row = NQ - 1;           // clamp; stores guarded
            const float* xr = src + (size_t)row * CC + kq * 8;
            #pragma unroll
            for (int kb = 0; kb < 4; ++kb)
                bfrag[mt][kb] = cvt8(xr + kb * 32);
        }
    };

    // 8 column tiles: LDS A-frags x register B-frags -> 2x f32x4 acc -> store
    auto runTiles = [&](const bf16x8 (&bfrag)[2][4], const float* __restrict__ bias,
                        short* __restrict__ dstb, int dstride, int hoff){
        #pragma unroll
        for (int t = 0; t < 8; ++t) {
            bf16x8 af[4];
            #pragma unroll
            for (int kb = 0; kb < 4; ++kb)
                af[kb] = *reinterpret_cast<const bf16x8*>(
                    &lds16[(((t * 4 + kb) << 6) + lane) * 8]);

            f32x4 acc0 = {0.f,0.f,0.f,0.f}, acc1 = {0.f,0.f,0.f,0.f};
            #pragma unroll
            for (int kb = 0; kb < 4; ++kb) {
                acc0 = __builtin_amdgcn_mfma_f32_16x16x32_bf16(af[kb], bfrag[0][kb], acc0, 0, 0, 0);
                acc1 = __builtin_amdgcn_mfma_f32_16x16x32_bf16(af[kb], bfrag[1][kb], acc1, 0, 0, 0);
            }

            const f32x4 bi = *reinterpret_cast<const f32x4*>(bias + t * 16 + kq * 4);
            #pragma unroll
            for (int mt = 0; mt < 2; ++mt) {
                const int row = base + mt * 16 + r;
                if (row < NQ) {
                    const f32x4 a = mt ? acc1 : acc0;
                    u32x2 pk;
                    pk[0] = (unsigned)f2bfu(a[0] + bi[0]) | ((unsigned)f2bfu(a[1] + bi[1]) << 16);
                    pk[1] = (unsigned)f2bfu(a[2] + bi[2]) | ((unsigned)f2bfu(a[3] + bi[3]) << 16);
                    *reinterpret_cast<u32x2*>(
                        dstb + (size_t)row * dstride + hoff + t * 16 + kq * 4) = pk;
                }
            }
        }
    };

    if (blockIdx.y == 0) {
        bf16x8 bfrag[2][4];
        loadB(x, bfrag);
        stageW(Wq);
        __syncthreads();
        runTiles(bfrag, bq, (short*)Qf, CC, 0);
    } else {
        bf16x8 bfrag[2][4];
        loadB(x2, bfrag);                 // x2 read once for BOTH K and V
        stageW(Wk);
        __syncthreads();
        runTiles(bfrag, bk, (short*)KVf, 2 * CC, 0);
        __syncthreads();                  // drain phase-1 ds_reads
        stageW(Wv);
        __syncthreads();
        runTiles(bfrag, bv, (short*)KVf, 2 * CC, CC);
    }
}

// ---------------------------------------------------------------------------
// Kernel 2: fused gather + positional MLP + grouped attention.
// One thread per (query n, group g). Online softmax in chunks of 4:
// 8 gather loads (4 K + 4 V) issued together, 4 logits, chunk max, ONE
// acc rescale per chunk (vs 4). Exactly equal to sequential online softmax
// (round-3 lesson: PE term reaches ~250 — unshifted exp overflows).
// Logit via expansion: 0.25*(k.q + prq*Sk + prk*Sq + 16*prk*prq), Sq hoisted.
// All loads/stores plain (round-6: NT was a net loss).
// ---------------------------------------------------------------------------
__global__ __launch_bounds__(256, 4) void attn_kernel(
    const float* __restrict__ p,        // (NQ,3)
    const float* __restrict__ p2,       // (NKV,3)
    const int*   __restrict__ idx,      // (NQ,SS)
    const float* __restrict__ W1,       // (3,3)
    const float* __restrict__ b1,       // (3,)
    const float* __restrict__ bn_gamma,
    const float* __restrict__ bn_beta,
    const float* __restrict__ bn_mean,
    const float* __restrict__ bn_var,
    const float* __restrict__ W2,       // (16,3)
    const float* __restrict__ b2,       // (16,)
    const __hip_bfloat16* __restrict__ Qf,   // (NQ,128) bf16
    const __hip_bfloat16* __restrict__ KVf,  // (NKV,256) bf16 interleaved
    float* __restrict__ out)            // (NQ,CC) f32
{
    const int tid = blockIdx.x * 256 + threadIdx.x;
    if (tid >= NQ * GG) return;
    const int n = tid >> 3;
    const int g = tid & 7;

    // --- fold BN into the 3x3 conv ---
    float fw1[3][3], fb1[3];
    #pragma unroll
    for (int j = 0; j < 3; ++j) {
        const float sc = bn_gamma[j] * rsqrtf(bn_var[j] + 1e-5f);
        #pragma unroll
        for (int k = 0; k < 3; ++k) fw1[j][k] = W1[j*3 + k] * sc;
        fb1[j] = (b1[j] - bn_mean[j]) * sc + bn_beta[j];
    }
    const float w2q0 = W2[g*3+0],     w2q1 = W2[g*3+1],     w2q2 = W2[g*3+2];
    const float w2k0 = W2[(g+8)*3+0], w2k1 = W2[(g+8)*3+1], w2k2 = W2[(g+8)*3+2];
    const float b2q = b2[g], b2k = b2[g+8];

    const float px = p[(size_t)n*3+0];
    const float py = p[(size_t)n*3+1];
    const float pz = p[(size_t)n*3+2];

    // --- query fragment + its channel sum ---
    float q[CSH];
    load16bf(Qf + (size_t)n * CC + g * CSH, q);
    float Sq = 0.f;
    #pragma unroll
    for (int c = 0; c < CSH; ++c) Sq += q[c];

    const i32x4* ip = reinterpret_cast<const i32x4*>(idx + (size_t)n * SS);

    float acc[CSH];
    #pragma unroll
    for (int c = 0; c < CSH; ++c) acc[c] = 0.f;
    float sum = 0.f;
    float m = -3.0e38f;

    #pragma unroll
    for (int sc = 0; sc < 4; ++sc) {
        const i32x4 i4 = ip[sc];

        // --- issue all 8 KV gathers + 4 p2 gathers for this chunk ---
        u32x4 kr[4][2], vr[4][2];
        float rx[4], ry[4], rz[4];
        #pragma unroll
        for (int j = 0; j < 4; ++j) {
            const int i = i4[j];
            const u32x4* b = reinterpret_cast<const u32x4*>(
                KVf + (size_t)i * (2 * CC) + g * CSH);
            kr[j][0] = b[0];  kr[j][1] = b[1];    // K slice (+0)
            vr[j][0] = b[16]; vr[j][1] = b[17];   // V slice (+256 B)
            rx[j] = p2[(size_t)i*3+0] - px;
            ry[j] = p2[(size_t)i*3+1] - py;
            rz[j] = p2[(size_t)i*3+2] - pz;
        }

        // --- 4 logits ---
        float d[4];
        #pragma unroll
        for (int j = 0; j < 4; ++j) {
            const float h0 = fmaxf(fw1[0][0]*rx[j] + fw1[0][1]*ry[j] + fw1[0][2]*rz[j] + fb1[0], 0.f);
            const float h1 = fmaxf(fw1[1][0]*rx[j] + fw1[1][1]*ry[j] + fw1[1][2]*rz[j] + fb1[1], 0.f);
            const float h2 = fmaxf(fw1[2][0]*rx[j] + fw1[2][1]*ry[j] + fw1[2][2]*rz[j] + fb1[2], 0.f);
            const float prq = w2q0*h0 + w2q1*h1 + w2q2*h2 + b2q;
            const float prk = w2k0*h0 + w2k1*h1 + w2k2*h2 + b2k;

            float kq = 0.f, Sk = 0.f;
            #pragma unroll
            for (int h = 0; h < 2; ++h) {
                const u32x4 a = kr[j][h];
                #pragma unroll
                for (int w4 = 0; w4 < 4; ++w4) {
                    const float lo = bf_lo(a[w4]), hi = bf_hi(a[w4]);
                    const int c = h*8 + w4*2;
                    kq += lo * q[c] + hi * q[c+1];
                    Sk += lo + hi;
                }
            }
            d[j] = 0.25f * (kq + prq * Sk + prk * Sq + 16.f * prk * prq);
        }

        // --- chunk max, one rescale, 4 weighted-V accumulates ---
        const float m4 = fmaxf(fmaxf(fmaxf(d[0], d[1]), fmaxf(d[2], d[3])), m);
        const float corr = __expf(m - m4);     // 0 on first chunk (m=-3e38)
        float wj[4];
        #pragma unroll
        for (int j = 0; j < 4; ++j) wj[j] = __expf(d[j] - m4);
        sum = sum * corr + wj[0] + wj[1] + wj[2] + wj[3];
        #pragma unroll
        for (int c = 0; c < CSH; ++c) acc[c] *= corr;
        #pragma unroll
        for (int j = 0; j < 4; ++j) {
            #pragma unroll
            for (int h = 0; h < 2; ++h) {
                const u32x4 a = vr[j][h];
                #pragma unroll
                for (int w4 = 0; w4 < 4; ++w4) {
                    const int c = h*8 + w4*2;
                    acc[c]   += wj[j] * bf_lo(a[w4]);
                    acc[c+1] += wj[j] * bf_hi(a[w4]);
                }
            }
        }
        m = m4;
    }

    const float inv = 1.f / sum;

    // --- store 16 f32 (64B; 8 lanes of one n cover 512B contiguous) ---
    f32x4* op = reinterpret_cast<f32x4*>(out + (size_t)n * CC + g * CSH);
    f32x4 o0 = {acc[0]*inv,  acc[1]*inv,  acc[2]*inv,  acc[3]*inv};
    f32x4 o1 = {acc[4]*inv,  acc[5]*inv,  acc[6]*inv,  acc[7]*inv};
    f32x4 o2 = {acc[8]*inv,  acc[9]*inv,  acc[10]*inv, acc[11]*inv};
    f32x4 o3 = {acc[12]*inv, acc[13]*inv, acc[14]*inv, acc[15]*inv};
    op[0] = o0; op[1] = o1; op[2] = o2; op[3] = o3;
}

// ---------------------------------------------------------------------------
extern "C" void kernel_launch(void* const* d_in, const int* in_sizes, int n_in,
                              void* d_out, int out_size, void* d_ws, size_t ws_size,
                              hipStream_t stream) {
    const float* p   = (const float*)d_in[0];
    const float* x   = (const float*)d_in[1];
    const float* p2  = (const float*)d_in[2];
    const float* x2  = (const float*)d_in[3];
    const int*   idx = (const int*)d_in[4];
    const float* Wq  = (const float*)d_in[5];
    const float* bq  = (const float*)d_in[6];
    const float* Wk  = (const float*)d_in[7];
    const float* bk  = (const float*)d_in[8];
    const float* Wv  = (const float*)d_in[9];
    const float* bv  = (const float*)d_in[10];
    const float* W1  = (const float*)d_in[11];
    const float* b1  = (const float*)d_in[12];
    const float* bng = (const float*)d_in[13];
    const float* bnb = (const float*)d_in[14];
    const float* bnm = (const float*)d_in[15];
    const float* bnv = (const float*)d_in[16];
    const float* W2  = (const float*)d_in[17];
    const float* b2  = (const float*)d_in[18];
    float* out = (float*)d_out;

    // workspace: Qf (12.8 MB) | KVf interleaved (25.6 MB)
    __hip_bfloat16* Qf  = (__hip_bfloat16*)d_ws;
    __hip_bfloat16* KVf = Qf + (size_t)NQ * CC;

    // y=0: Q; y=1: K+V fused (x2 read once)
    qkv_gemm<<<dim3(391, 2), 256, 0, stream>>>(
        x, x2, Wq, Wk, Wv, bq, bk, bv, Qf, KVf);

    const int nthreads = NQ * GG;
    attn_kernel<<<(nthreads + 255) / 256, 256, 0, stream>>>(
        p, p2, idx, W1, b1, bng, bnb, bnm, bnv, W2, b2, Qf, KVf, out);
}

// Round 8
// 212.213 us; speedup vs baseline: 2.8663x; 2.8663x over previous
//
#include <hip/hip_runtime.h>
#include <hip/hip_bf16.h>

#define NQ   50000
#define NKV  50000
#define CC   128
#define GG   8
#define SS   16
#define CSH  16

typedef short    bf16x8 __attribute__((ext_vector_type(8)));
typedef float    f32x4  __attribute__((ext_vector_type(4)));
typedef unsigned u32x4  __attribute__((ext_vector_type(4)));
typedef unsigned u32x2  __attribute__((ext_vector_type(2)));
typedef int      i32x4  __attribute__((ext_vector_type(4)));

__device__ __forceinline__ float bf_lo(unsigned u){ union{unsigned x; float f;} v; v.x = u << 16;        return v.f; }
__device__ __forceinline__ float bf_hi(unsigned u){ union{unsigned x; float f;} v; v.x = u & 0xffff0000u; return v.f; }
__device__ __forceinline__ unsigned short f2bfu(float f){
    __hip_bfloat16 h = __float2bfloat16(f);
    return *reinterpret_cast<unsigned short*>(&h);
}
__device__ __forceinline__ short f2bfs(float f){
    __hip_bfloat16 h = __float2bfloat16(f);
    return *reinterpret_cast<short*>(&h);
}

// Load 16 contiguous bf16 (32B, >=16B aligned) -> 16 fp32
__device__ __forceinline__ void load16bf(const __hip_bfloat16* ptr, float* o){
    const u32x4* p4 = reinterpret_cast<const u32x4*>(ptr);
    u32x4 a = p4[0]; u32x4 b = p4[1];
    o[0]=bf_lo(a[0]);  o[1]=bf_hi(a[0]);  o[2]=bf_lo(a[1]);  o[3]=bf_hi(a[1]);
    o[4]=bf_lo(a[2]);  o[5]=bf_hi(a[2]);  o[6]=bf_lo(a[3]);  o[7]=bf_hi(a[3]);
    o[8]=bf_lo(b[0]);  o[9]=bf_hi(b[0]);  o[10]=bf_lo(b[1]); o[11]=bf_hi(b[1]);
    o[12]=bf_lo(b[2]); o[13]=bf_hi(b[2]); o[14]=bf_lo(b[3]); o[15]=bf_hi(b[3]);
}

// Load 8 contiguous f32 (32B), convert to bf16x8 fragment
__device__ __forceinline__ bf16x8 cvt8(const float* p){
    const f32x4* q = reinterpret_cast<const f32x4*>(p);
    f32x4 u = q[0], v = q[1];
    bf16x8 r;
    r[0]=f2bfs(u[0]); r[1]=f2bfs(u[1]); r[2]=f2bfs(u[2]); r[3]=f2bfs(u[3]);
    r[4]=f2bfs(v[0]); r[5]=f2bfs(v[1]); r[6]=f2bfs(v[2]); r[7]=f2bfs(v[3]);
    return r;
}

// ---------------------------------------------------------------------------
// Kernel 1: Q/K/V projections — UNIFORM blocks (r7 lesson: (391,2) grid had
// 2x work imbalance between y=0 and y=1). 782 blocks x 256 threads; each
// block computes Q, K, AND V for 64 rows (16 rows/wave/projection).
// x2 rows read once and reused for K and V. W staged per projection into
// 32 KB LDS in MFMA A-fragment order (lane-contiguous ds_read_b128).
// Plain stores (r6 lesson: NT stores = write amplification).
// K/V land interleaved in KVf rows of 256 elems: [K 0..127 | V 128..255].
// ---------------------------------------------------------------------------
__global__ __launch_bounds__(256) void qkv_gemm(
    const float* __restrict__ x,
    const float* __restrict__ x2,
    const float* __restrict__ Wq, const float* __restrict__ Wk,
    const float* __restrict__ Wv,
    const float* __restrict__ bq, const float* __restrict__ bk,
    const float* __restrict__ bv,
    __hip_bfloat16* __restrict__ Qf,     // (NQ, 128)
    __hip_bfloat16* __restrict__ KVf)    // (NKV, 256) interleaved K|V
{
    __shared__ short lds16[16384];   // 32 KB: 8 tiles x 4 kb x 64 lanes x 8 halfwords

    const int tid  = threadIdx.x;
    const int wave = tid >> 6;
    const int lane = tid & 63;
    const int r    = lane & 15;
    const int kq   = lane >> 4;
    const int wbase = blockIdx.x * 64 + wave * 16;   // this wave's 16 rows

    // stage one 128x128 f32 W into LDS (bf16, MFMA A-fragment order),
    // lane-contiguous global reads (32B lane stride -> full cache lines)
    auto stageW = [&](const float* __restrict__ W){
        #pragma unroll
        for (int i = 0; i < 8; ++i) {
            const int o   = i * 2048 + tid * 8;    // linear f32 offset in W
            const bf16x8 v = cvt8(W + o);
            const int row = o >> 7, col = o & 127;
            const int lchunk = (((row >> 4) * 4 + (col >> 5)) << 6)
                             + (((col >> 3) & 3) << 4) + (row & 15);
            *reinterpret_cast<bf16x8*>(&lds16[lchunk * 8]) = v;
        }
    };

    // load this wave's 16 source rows as B-fragments (4 k-blocks)
    auto loadB = [&](const float* __restrict__ src, bf16x8 (&bfrag)[4]){
        int row = wbase + r;
        if (row >= NQ) row = NQ - 1;               // clamp; stores guarded
        const float* xr = src + (size_t)row * CC + kq * 8;
        #pragma unroll
        for (int kb = 0; kb < 4; ++kb)
            bfrag[kb] = cvt8(xr + kb * 32);
    };

    // 8 column tiles: LDS A-frags x register B-frags -> f32x4 acc -> store
    auto runTiles = [&](const bf16x8 (&bfrag)[4], const float* __restrict__ bias,
                        short* __restrict__ dstb, int dstride, int hoff){
        const int row = wbase + r;
        #pragma unroll
        for (int t = 0; t < 8; ++t) {
            bf16x8 af[4];
            #pragma unroll
            for (int kb = 0; kb < 4; ++kb)
                af[kb] = *reinterpret_cast<const bf16x8*>(
                    &lds16[(((t * 4 + kb) << 6) + lane) * 8]);

            f32x4 acc = {0.f,0.f,0.f,0.f};
            #pragma unroll
            for (int kb = 0; kb < 4; ++kb)
                acc = __builtin_amdgcn_mfma_f32_16x16x32_bf16(af[kb], bfrag[kb], acc, 0, 0, 0);

            const f32x4 bi = *reinterpret_cast<const f32x4*>(bias + t * 16 + kq * 4);
            if (row < NQ) {
                u32x2 pk;
                pk[0] = (unsigned)f2bfu(acc[0] + bi[0]) | ((unsigned)f2bfu(acc[1] + bi[1]) << 16);
                pk[1] = (unsigned)f2bfu(acc[2] + bi[2]) | ((unsigned)f2bfu(acc[3] + bi[3]) << 16);
                *reinterpret_cast<u32x2*>(
                    dstb + (size_t)row * dstride + hoff + t * 16 + kq * 4) = pk;
            }
        }
    };

    bf16x8 fq[4], fkv[4];
    loadB(x,  fq);                    // 16 x-rows   (for Q)
    loadB(x2, fkv);                   // 16 x2-rows  (for K AND V — read once)

    stageW(Wq);
    __syncthreads();
    runTiles(fq, bq, (short*)Qf, CC, 0);
    __syncthreads();                  // drain ds_reads before restage
    stageW(Wk);
    __syncthreads();
    runTiles(fkv, bk, (short*)KVf, 2 * CC, 0);
    __syncthreads();
    stageW(Wv);
    __syncthreads();
    runTiles(fkv, bv, (short*)KVf, 2 * CC, CC);
}

// ---------------------------------------------------------------------------
// Kernel 2: fused gather + positional MLP + grouped attention, single pass,
// online (flash-style) softmax — EXACT round-4 structure (60 VGPR, no
// spill; r7 lesson: chunked register-staging + min-waves bound spilled to
// scratch, 1.5 GB of traffic). Only delta vs r4: KVf interleaved rows
// (one base address per neighbor, K at +0, V at +256 B).
// Round-3 lesson kept: PE term reaches ~250 — unshifted exp overflows.
// ---------------------------------------------------------------------------
__global__ __launch_bounds__(256) void attn_kernel(
    const float* __restrict__ p,        // (NQ,3)
    const float* __restrict__ p2,       // (NKV,3)
    const int*   __restrict__ idx,      // (NQ,SS)
    const float* __restrict__ W1,       // (3,3)
    const float* __restrict__ b1,       // (3,)
    const float* __restrict__ bn_gamma,
    const float* __restrict__ bn_beta,
    const float* __restrict__ bn_mean,
    const float* __restrict__ bn_var,
    const float* __restrict__ W2,       // (16,3)
    const float* __restrict__ b2,       // (16,)
    const __hip_bfloat16* __restrict__ Qf,   // (NQ,128) bf16
    const __hip_bfloat16* __restrict__ KVf,  // (NKV,256) bf16 interleaved
    float* __restrict__ out)            // (NQ,CC) f32
{
    const int tid = blockIdx.x * 256 + threadIdx.x;
    if (tid >= NQ * GG) return;
    const int n = tid >> 3;
    const int g = tid & 7;

    // --- fold BN into the 3x3 conv ---
    float fw1[3][3], fb1[3];
    #pragma unroll
    for (int j = 0; j < 3; ++j) {
        const float sc = bn_gamma[j] * rsqrtf(bn_var[j] + 1e-5f);
        #pragma unroll
        for (int k = 0; k < 3; ++k) fw1[j][k] = W1[j*3 + k] * sc;
        fb1[j] = (b1[j] - bn_mean[j]) * sc + bn_beta[j];
    }
    const float w2q0 = W2[g*3+0],     w2q1 = W2[g*3+1],     w2q2 = W2[g*3+2];
    const float w2k0 = W2[(g+8)*3+0], w2k1 = W2[(g+8)*3+1], w2k2 = W2[(g+8)*3+2];
    const float b2q = b2[g], b2k = b2[g+8];

    const float px = p[(size_t)n*3+0];
    const float py = p[(size_t)n*3+1];
    const float pz = p[(size_t)n*3+2];

    // --- neighbor indices (16 ints = 64B aligned) ---
    int nbr[SS];
    {
        const i32x4* ip = reinterpret_cast<const i32x4*>(idx + (size_t)n * SS);
        i32x4 i0 = ip[0], i1 = ip[1], i2 = ip[2], i3 = ip[3];
        nbr[0]=i0[0]; nbr[1]=i0[1]; nbr[2]=i0[2]; nbr[3]=i0[3];
        nbr[4]=i1[0]; nbr[5]=i1[1]; nbr[6]=i1[2]; nbr[7]=i1[3];
        nbr[8]=i2[0]; nbr[9]=i2[1]; nbr[10]=i2[2]; nbr[11]=i2[3];
        nbr[12]=i3[0]; nbr[13]=i3[1]; nbr[14]=i3[2]; nbr[15]=i3[3];
    }

    // --- query fragment for this group ---
    float q[CSH];
    load16bf(Qf + (size_t)n * CC + g * CSH, q);

    // --- single fused pass with online softmax ---
    float acc[CSH];
    #pragma unroll
    for (int c = 0; c < CSH; ++c) acc[c] = 0.f;
    float sum = 0.f;
    float m = -3.0e38f;

    #pragma unroll 4
    for (int s = 0; s < SS; ++s) {
        const int i = nbr[s];
        const __hip_bfloat16* kv = KVf + (size_t)i * (2 * CC) + g * CSH;

        float kk[CSH], vv[CSH];
        load16bf(kv, kk);            // K slice at +0
        load16bf(kv + CC, vv);       // V slice at +256 B immediate

        const float rx = p2[(size_t)i*3+0] - px;
        const float ry = p2[(size_t)i*3+1] - py;
        const float rz = p2[(size_t)i*3+2] - pz;
        const float h0 = fmaxf(fw1[0][0]*rx + fw1[0][1]*ry + fw1[0][2]*rz + fb1[0], 0.f);
        const float h1 = fmaxf(fw1[1][0]*rx + fw1[1][1]*ry + fw1[1][2]*rz + fb1[1], 0.f);
        const float h2 = fmaxf(fw1[2][0]*rx + fw1[2][1]*ry + fw1[2][2]*rz + fb1[2], 0.f);
        const float prq = w2q0*h0 + w2q1*h1 + w2q2*h2 + b2q;
        const float prk = w2k0*h0 + w2k1*h1 + w2k2*h2 + b2k;

        float d = 0.f;
        #pragma unroll
        for (int c = 0; c < CSH; ++c) d += (kk[c] + prk) * (q[c] + prq);
        d *= 0.25f;   // 1/sqrt(CS) = 0.25

        const float mnew = fmaxf(m, d);
        const float corr = __expf(m - mnew);   // 1.0 when max unchanged
        const float w    = __expf(d - mnew);
        sum = sum * corr + w;
        #pragma unroll
        for (int c = 0; c < CSH; ++c) acc[c] = acc[c] * corr + w * vv[c];
        m = mnew;
    }

    const float inv = 1.f / sum;

    // --- store 16 f32 (64B; 8 lanes of one n cover 512B contiguous) ---
    f32x4* op = reinterpret_cast<f32x4*>(out + (size_t)n * CC + g * CSH);
    f32x4 o0 = {acc[0]*inv,  acc[1]*inv,  acc[2]*inv,  acc[3]*inv};
    f32x4 o1 = {acc[4]*inv,  acc[5]*inv,  acc[6]*inv,  acc[7]*inv};
    f32x4 o2 = {acc[8]*inv,  acc[9]*inv,  acc[10]*inv, acc[11]*inv};
    f32x4 o3 = {acc[12]*inv, acc[13]*inv, acc[14]*inv, acc[15]*inv};
    op[0] = o0; op[1] = o1; op[2] = o2; op[3] = o3;
}

// ---------------------------------------------------------------------------
extern "C" void kernel_launch(void* const* d_in, const int* in_sizes, int n_in,
                              void* d_out, int out_size, void* d_ws, size_t ws_size,
                              hipStream_t stream) {
    const float* p   = (const float*)d_in[0];
    const float* x   = (const float*)d_in[1];
    const float* p2  = (const float*)d_in[2];
    const float* x2  = (const float*)d_in[3];
    const int*   idx = (const int*)d_in[4];
    const float* Wq  = (const float*)d_in[5];
    const float* bq  = (const float*)d_in[6];
    const float* Wk  = (const float*)d_in[7];
    const float* bk  = (const float*)d_in[8];
    const float* Wv  = (const float*)d_in[9];
    const float* bv  = (const float*)d_in[10];
    const float* W1  = (const float*)d_in[11];
    const float* b1  = (const float*)d_in[12];
    const float* bng = (const float*)d_in[13];
    const float* bnb = (const float*)d_in[14];
    const float* bnm = (const float*)d_in[15];
    const float* bnv = (const float*)d_in[16];
    const float* W2  = (const float*)d_in[17];
    const float* b2  = (const float*)d_in[18];
    float* out = (float*)d_out;

    // workspace: Qf (12.8 MB) | KVf interleaved (25.6 MB)
    __hip_bfloat16* Qf  = (__hip_bfloat16*)d_ws;
    __hip_bfloat16* KVf = Qf + (size_t)NQ * CC;

    // 50000 rows / 64 rows-per-block = 781.25 -> 782 uniform blocks (Q+K+V)
    qkv_gemm<<<dim3(782), 256, 0, stream>>>(
        x, x2, Wq, Wk, Wv, bq, bk, bv, Qf, KVf);

    const int nthreads = NQ * GG;
    attn_kernel<<<(nthreads + 255) / 256, 256, 0, stream>>>(
        p, p2, idx, W1, b1, bng, bnb, bnm, bnv, W2, b2, Qf, KVf, out);
}

// Round 9
// 210.501 us; speedup vs baseline: 2.8896x; 1.0081x over previous
//
#include <hip/hip_runtime.h>
#include <hip/hip_bf16.h>

#define NQ   50000
#define NKV  50000
#define CC   128
#define GG   8
#define SS   16
#define CSH  16

typedef short    bf16x8 __attribute__((ext_vector_type(8)));
typedef float    f32x4  __attribute__((ext_vector_type(4)));
typedef unsigned u32x4  __attribute__((ext_vector_type(4)));
typedef unsigned u32x2  __attribute__((ext_vector_type(2)));
typedef int      i32x4  __attribute__((ext_vector_type(4)));

__device__ __forceinline__ float bf_lo(unsigned u){ union{unsigned x; float f;} v; v.x = u << 16;        return v.f; }
__device__ __forceinline__ float bf_hi(unsigned u){ union{unsigned x; float f;} v; v.x = u & 0xffff0000u; return v.f; }
__device__ __forceinline__ unsigned short f2bfu(float f){
    __hip_bfloat16 h = __float2bfloat16(f);
    return *reinterpret_cast<unsigned short*>(&h);
}
__device__ __forceinline__ short f2bfs(float f){
    __hip_bfloat16 h = __float2bfloat16(f);
    return *reinterpret_cast<short*>(&h);
}

// Load 16 contiguous bf16 (32B, >=16B aligned) -> 16 fp32
__device__ __forceinline__ void load16bf(const __hip_bfloat16* ptr, float* o){
    const u32x4* p4 = reinterpret_cast<const u32x4*>(ptr);
    u32x4 a = p4[0]; u32x4 b = p4[1];
    o[0]=bf_lo(a[0]);  o[1]=bf_hi(a[0]);  o[2]=bf_lo(a[1]);  o[3]=bf_hi(a[1]);
    o[4]=bf_lo(a[2]);  o[5]=bf_hi(a[2]);  o[6]=bf_lo(a[3]);  o[7]=bf_hi(a[3]);
    o[8]=bf_lo(b[0]);  o[9]=bf_hi(b[0]);  o[10]=bf_lo(b[1]); o[11]=bf_hi(b[1]);
    o[12]=bf_lo(b[2]); o[13]=bf_hi(b[2]); o[14]=bf_lo(b[3]); o[15]=bf_hi(b[3]);
}

// Load 8 contiguous f32 (32B), convert to bf16x8 fragment
__device__ __forceinline__ bf16x8 cvt8(const float* p){
    const f32x4* q = reinterpret_cast<const f32x4*>(p);
    f32x4 u = q[0], v = q[1];
    bf16x8 r;
    r[0]=f2bfs(u[0]); r[1]=f2bfs(u[1]); r[2]=f2bfs(u[2]); r[3]=f2bfs(u[3]);
    r[4]=f2bfs(v[0]); r[5]=f2bfs(v[1]); r[6]=f2bfs(v[2]); r[7]=f2bfs(v[3]);
    return r;
}

// ---------------------------------------------------------------------------
// Kernel 1: Q/K/V projections, K+V fused, 32 rows/wave (r8 lesson: 16
// rows/wave gave 1:1 ds_read:MFMA — LDS-pipe-bound; 2 m-tiles amortize the
// same 32 ds_read_b128 over 64 MFMA). 391 blocks x 256 threads; each block
// computes Q, K AND V for 128 rows. x/x2 fragments (16 bf16x8 regs) are
// held across all three phases -> x2 read ONCE. W staged per projection
// into 32 KB LDS in MFMA A-fragment order (lane-contiguous ds_read_b128;
// staging global reads lane-contiguous, 32B stride).
// Plain stores (r6 lesson: NT stores = write amplification).
// K/V land interleaved in KVf rows of 256 elems: [K 0..127 | V 128..255].
// ---------------------------------------------------------------------------
__global__ __launch_bounds__(256) void qkv_gemm(
    const float* __restrict__ x,
    const float* __restrict__ x2,
    const float* __restrict__ Wq, const float* __restrict__ Wk,
    const float* __restrict__ Wv,
    const float* __restrict__ bq, const float* __restrict__ bk,
    const float* __restrict__ bv,
    __hip_bfloat16* __restrict__ Qf,     // (NQ, 128)
    __hip_bfloat16* __restrict__ KVf)    // (NKV, 256) interleaved K|V
{
    __shared__ short lds16[16384];   // 32 KB: 8 tiles x 4 kb x 64 lanes x 8 halfwords

    const int tid  = threadIdx.x;
    const int wave = tid >> 6;
    const int lane = tid & 63;
    const int r    = lane & 15;
    const int kq   = lane >> 4;
    const int base = blockIdx.x * 128 + wave * 32;   // this wave's 32 rows

    // stage one 128x128 f32 W into LDS (bf16, MFMA A-fragment order),
    // lane-contiguous global reads (32B lane stride -> full cache lines)
    auto stageW = [&](const float* __restrict__ W){
        #pragma unroll
        for (int i = 0; i < 8; ++i) {
            const int o   = i * 2048 + tid * 8;    // linear f32 offset in W
            const bf16x8 v = cvt8(W + o);
            const int row = o >> 7, col = o & 127;
            const int lchunk = (((row >> 4) * 4 + (col >> 5)) << 6)
                             + (((col >> 3) & 3) << 4) + (row & 15);
            *reinterpret_cast<bf16x8*>(&lds16[lchunk * 8]) = v;
        }
    };

    // load this wave's 32 source rows as B-fragments (2 m-tiles x 4 k-blocks)
    auto loadB = [&](const float* __restrict__ src, bf16x8 (&bfrag)[2][4]){
        #pragma unroll
        for (int mt = 0; mt < 2; ++mt) {
            int row = base + mt * 16 + r;
            if (row >= NQ) row = NQ - 1;           // clamp; stores guarded
            const float* xr = src + (size_t)row * CC + kq * 8;
            #pragma unroll
            for (int kb = 0; kb < 4; ++kb)
                bfrag[mt][kb] = cvt8(xr + kb * 32);
        }
    };

    // 8 column tiles: LDS A-frags x register B-frags -> 2x f32x4 acc -> store
    auto runTiles = [&](const bf16x8 (&bfrag)[2][4], const float* __restrict__ bias,
                        short* __restrict__ dstb, int dstride, int hoff){
        #pragma unroll
        for (int t = 0; t < 8; ++t) {
            bf16x8 af[4];
            #pragma unroll
            for (int kb = 0; kb < 4; ++kb)
                af[kb] = *reinterpret_cast<const bf16x8*>(
                    &lds16[(((t * 4 + kb) << 6) + lane) * 8]);

            f32x4 acc0 = {0.f,0.f,0.f,0.f}, acc1 = {0.f,0.f,0.f,0.f};
            #pragma unroll
            for (int kb = 0; kb < 4; ++kb) {
                acc0 = __builtin_amdgcn_mfma_f32_16x16x32_bf16(af[kb], bfrag[0][kb], acc0, 0, 0, 0);
                acc1 = __builtin_amdgcn_mfma_f32_16x16x32_bf16(af[kb], bfrag[1][kb], acc1, 0, 0, 0);
            }

            const f32x4 bi = *reinterpret_cast<const f32x4*>(bias + t * 16 + kq * 4);
            #pragma unroll
            for (int mt = 0; mt < 2; ++mt) {
                const int row = base + mt * 16 + r;
                if (row < NQ) {
                    const f32x4 a = mt ? acc1 : acc0;
                    u32x2 pk;
                    pk[0] = (unsigned)f2bfu(a[0] + bi[0]) | ((unsigned)f2bfu(a[1] + bi[1]) << 16);
                    pk[1] = (unsigned)f2bfu(a[2] + bi[2]) | ((unsigned)f2bfu(a[3] + bi[3]) << 16);
                    *reinterpret_cast<u32x2*>(
                        dstb + (size_t)row * dstride + hoff + t * 16 + kq * 4) = pk;
                }
            }
        }
    };

    bf16x8 fq[2][4], fkv[2][4];
    loadB(x,  fq);                    // 32 x-rows   (for Q)
    loadB(x2, fkv);                   // 32 x2-rows  (for K AND V — read once)

    stageW(Wq);
    __syncthreads();
    runTiles(fq, bq, (short*)Qf, CC, 0);
    __syncthreads();                  // drain ds_reads before restage
    stageW(Wk);
    __syncthreads();
    runTiles(fkv, bk, (short*)KVf, 2 * CC, 0);
    __syncthreads();
    stageW(Wv);
    __syncthreads();
    runTiles(fkv, bv, (short*)KVf, 2 * CC, CC);
}

// ---------------------------------------------------------------------------
// Kernel 2: fused gather + positional MLP + grouped attention, single pass,
// online (flash-style) softmax — UNCHANGED from round 8 (clean attribution;
// r7 lesson: no register-array staging, no min-waves bound).
// Round-3 lesson kept: PE term reaches ~250 — unshifted exp overflows.
// ---------------------------------------------------------------------------
__global__ __launch_bounds__(256) void attn_kernel(
    const float* __restrict__ p,        // (NQ,3)
    const float* __restrict__ p2,       // (NKV,3)
    const int*   __restrict__ idx,      // (NQ,SS)
    const float* __restrict__ W1,       // (3,3)
    const float* __restrict__ b1,       // (3,)
    const float* __restrict__ bn_gamma,
    const float* __restrict__ bn_beta,
    const float* __restrict__ bn_mean,
    const float* __restrict__ bn_var,
    const float* __restrict__ W2,       // (16,3)
    const float* __restrict__ b2,       // (16,)
    const __hip_bfloat16* __restrict__ Qf,   // (NQ,128) bf16
    const __hip_bfloat16* __restrict__ KVf,  // (NKV,256) bf16 interleaved
    float* __restrict__ out)            // (NQ,CC) f32
{
    const int tid = blockIdx.x * 256 + threadIdx.x;
    if (tid >= NQ * GG) return;
    const int n = tid >> 3;
    const int g = tid & 7;

    // --- fold BN into the 3x3 conv ---
    float fw1[3][3], fb1[3];
    #pragma unroll
    for (int j = 0; j < 3; ++j) {
        const float sc = bn_gamma[j] * rsqrtf(bn_var[j] + 1e-5f);
        #pragma unroll
        for (int k = 0; k < 3; ++k) fw1[j][k] = W1[j*3 + k] * sc;
        fb1[j] = (b1[j] - bn_mean[j]) * sc + bn_beta[j];
    }
    const float w2q0 = W2[g*3+0],     w2q1 = W2[g*3+1],     w2q2 = W2[g*3+2];
    const float w2k0 = W2[(g+8)*3+0], w2k1 = W2[(g+8)*3+1], w2k2 = W2[(g+8)*3+2];
    const float b2q = b2[g], b2k = b2[g+8];

    const float px = p[(size_t)n*3+0];
    const float py = p[(size_t)n*3+1];
    const float pz = p[(size_t)n*3+2];

    // --- neighbor indices (16 ints = 64B aligned) ---
    int nbr[SS];
    {
        const i32x4* ip = reinterpret_cast<const i32x4*>(idx + (size_t)n * SS);
        i32x4 i0 = ip[0], i1 = ip[1], i2 = ip[2], i3 = ip[3];
        nbr[0]=i0[0]; nbr[1]=i0[1]; nbr[2]=i0[2]; nbr[3]=i0[3];
        nbr[4]=i1[0]; nbr[5]=i1[1]; nbr[6]=i1[2]; nbr[7]=i1[3];
        nbr[8]=i2[0]; nbr[9]=i2[1]; nbr[10]=i2[2]; nbr[11]=i2[3];
        nbr[12]=i3[0]; nbr[13]=i3[1]; nbr[14]=i3[2]; nbr[15]=i3[3];
    }

    // --- query fragment for this group ---
    float q[CSH];
    load16bf(Qf + (size_t)n * CC + g * CSH, q);

    // --- single fused pass with online softmax ---
    float acc[CSH];
    #pragma unroll
    for (int c = 0; c < CSH; ++c) acc[c] = 0.f;
    float sum = 0.f;
    float m = -3.0e38f;

    #pragma unroll 4
    for (int s = 0; s < SS; ++s) {
        const int i = nbr[s];
        const __hip_bfloat16* kv = KVf + (size_t)i * (2 * CC) + g * CSH;

        float kk[CSH], vv[CSH];
        load16bf(kv, kk);            // K slice at +0
        load16bf(kv + CC, vv);       // V slice at +256 B immediate

        const float rx = p2[(size_t)i*3+0] - px;
        const float ry = p2[(size_t)i*3+1] - py;
        const float rz = p2[(size_t)i*3+2] - pz;
        const float h0 = fmaxf(fw1[0][0]*rx + fw1[0][1]*ry + fw1[0][2]*rz + fb1[0], 0.f);
        const float h1 = fmaxf(fw1[1][0]*rx + fw1[1][1]*ry + fw1[1][2]*rz + fb1[1], 0.f);
        const float h2 = fmaxf(fw1[2][0]*rx + fw1[2][1]*ry + fw1[2][2]*rz + fb1[2], 0.f);
        const float prq = w2q0*h0 + w2q1*h1 + w2q2*h2 + b2q;
        const float prk = w2k0*h0 + w2k1*h1 + w2k2*h2 + b2k;

        float d = 0.f;
        #pragma unroll
        for (int c = 0; c < CSH; ++c) d += (kk[c] + prk) * (q[c] + prq);
        d *= 0.25f;   // 1/sqrt(CS) = 0.25

        const float mnew = fmaxf(m, d);
        const float corr = __expf(m - mnew);   // 1.0 when max unchanged
        const float w    = __expf(d - mnew);
        sum = sum * corr + w;
        #pragma unroll
        for (int c = 0; c < CSH; ++c) acc[c] = acc[c] * corr + w * vv[c];
        m = mnew;
    }

    const float inv = 1.f / sum;

    // --- store 16 f32 (64B; 8 lanes of one n cover 512B contiguous) ---
    f32x4* op = reinterpret_cast<f32x4*>(out + (size_t)n * CC + g * CSH);
    f32x4 o0 = {acc[0]*inv,  acc[1]*inv,  acc[2]*inv,  acc[3]*inv};
    f32x4 o1 = {acc[4]*inv,  acc[5]*inv,  acc[6]*inv,  acc[7]*inv};
    f32x4 o2 = {acc[8]*inv,  acc[9]*inv,  acc[10]*inv, acc[11]*inv};
    f32x4 o3 = {acc[12]*inv, acc[13]*inv, acc[14]*inv, acc[15]*inv};
    op[0] = o0; op[1] = o1; op[2] = o2; op[3] = o3;
}

// ---------------------------------------------------------------------------
extern "C" void kernel_launch(void* const* d_in, const int* in_sizes, int n_in,
                              void* d_out, int out_size, void* d_ws, size_t ws_size,
                              hipStream_t stream) {
    const float* p   = (const float*)d_in[0];
    const float* x   = (const float*)d_in[1];
    const float* p2  = (const float*)d_in[2];
    const float* x2  = (const float*)d_in[3];
    const int*   idx = (const int*)d_in[4];
    const float* Wq  = (const float*)d_in[5];
    const float* bq  = (const float*)d_in[6];
    const float* Wk  = (const float*)d_in[7];
    const float* bk  = (const float*)d_in[8];
    const float* Wv  = (const float*)d_in[9];
    const float* bv  = (const float*)d_in[10];
    const float* W1  = (const float*)d_in[11];
    const float* b1  = (const float*)d_in[12];
    const float* bng = (const float*)d_in[13];
    const float* bnb = (const float*)d_in[14];
    const float* bnm = (const float*)d_in[15];
    const float* bnv = (const float*)d_in[16];
    const float* W2  = (const float*)d_in[17];
    const float* b2  = (const float*)d_in[18];
    float* out = (float*)d_out;

    // workspace: Qf (12.8 MB) | KVf interleaved (25.6 MB)
    __hip_bfloat16* Qf  = (__hip_bfloat16*)d_ws;
    __hip_bfloat16* KVf = Qf + (size_t)NQ * CC;

    // 50000 rows / 128 rows-per-block = 390.6 -> 391 blocks (Q+K+V each)
    qkv_gemm<<<dim3(391), 256, 0, stream>>>(
        x, x2, Wq, Wk, Wv, bq, bk, bv, Qf, KVf);

    const int nthreads = NQ * GG;
    attn_kernel<<<(nthreads + 255) / 256, 256, 0, stream>>>(
        p, p2, idx, W1, b1, bng, bnb, bnm, bnv, W2, b2, Qf, KVf, out);
}